// Round 1
// baseline (332.178 us; speedup 1.0000x reference)
//
#include <hip/hip_runtime.h>
#include <hip/hip_bf16.h>
#include <math.h>

#define N_NODES  30000
#define N_EDGESR 480000
#define E_TOT    (N_EDGESR + N_NODES)
#define N_GRAPHS 64
#define IN_DIM   128
#define HID      64
#define NEG_SLOPE 0.2f

__device__ __forceinline__ float lrelu(float v) { return v > 0.f ? v : NEG_SLOPE * v; }

// ---------------- zero init (counts + pool) ----------------
__global__ void zero_kernel(int* __restrict__ counts, unsigned* __restrict__ g) {
    int t = blockIdx.x * 256 + threadIdx.x;
    if (t < N_NODES) counts[t] = 0;
    if (t < N_GRAPHS * HID) g[t] = 0u;
}

// ---------------- CSR build ----------------
__global__ void edge_hist(const int* __restrict__ ei, int* __restrict__ counts) {
    int e = blockIdx.x * blockDim.x + threadIdx.x;
    if (e >= E_TOT) return;
    int d = (e < N_EDGESR) ? ei[N_EDGESR + e] : (e - N_EDGESR);
    atomicAdd(&counts[d], 1);
}

__global__ __launch_bounds__(1024) void scan_counts(const int* __restrict__ counts,
                                                    int* __restrict__ rowstart,
                                                    int* __restrict__ cursor) {
    __shared__ int bufA[1024];
    __shared__ int bufB[1024];
    const int t = threadIdx.x;
    const int CH = 30;                 // 1024*30 = 30720 >= 30000
    int local[CH];
    int base = t * CH;
    int s = 0;
    #pragma unroll
    for (int i = 0; i < CH; ++i) {
        int idx = base + i;
        int c = (idx < N_NODES) ? counts[idx] : 0;
        local[i] = c; s += c;
    }
    bufA[t] = s;
    __syncthreads();
    int* a = bufA; int* b = bufB;
    for (int off = 1; off < 1024; off <<= 1) {
        int v = a[t] + ((t >= off) ? a[t - off] : 0);
        b[t] = v;
        __syncthreads();
        int* tmp = a; a = b; b = tmp;
    }
    int run = (t == 0) ? 0 : a[t - 1];   // exclusive prefix
    #pragma unroll
    for (int i = 0; i < CH; ++i) {
        int idx = base + i;
        if (idx < N_NODES) { rowstart[idx] = run; cursor[idx] = run; run += local[i]; }
    }
    if (t == 0) rowstart[N_NODES] = E_TOT;
}

__global__ void edge_scatter(const int* __restrict__ ei, int* __restrict__ cursor,
                             int* __restrict__ srcidx) {
    int e = blockIdx.x * blockDim.x + threadIdx.x;
    if (e >= E_TOT) return;
    int s, d;
    if (e < N_EDGESR) { s = ei[e]; d = ei[N_EDGESR + e]; }
    else              { s = d = e - N_EDGESR; }
    int pos = atomicAdd(&cursor[d], 1);
    srcidx[pos] = s;
}

// ---------------- tiled f32 GEMM: C[nrows,ncols] = A[nrows,KTOT] @ B[KTOT,ncols] ----------------
template<int KTOT>
__global__ __launch_bounds__(256) void gemm_tile(const float* __restrict__ A,
                                                 const float* __restrict__ B,
                                                 float* __restrict__ C,
                                                 int nrows, int ncols) {
    __shared__ float As[64][68];   // stride 68: 16B-aligned rows, <=2-way bank conflicts
    __shared__ float Bs[64][64];
    const int tid = threadIdx.x;
    const int rowbase = blockIdx.x * 64;
    const int colbase = blockIdx.y * 64;
    const int tr = tid >> 4;       // 0..15
    const int tc = tid & 15;       // 0..15
    float acc[4][4] = {};

    for (int kt = 0; kt < KTOT; kt += 64) {
        #pragma unroll
        for (int it = 0; it < 4; ++it) {
            int flat = it * 256 + tid;        // 0..1023
            int r = flat >> 4, c4 = flat & 15;
            int grow = rowbase + r; if (grow >= nrows) grow = nrows - 1;
            float4 v = *reinterpret_cast<const float4*>(&A[(size_t)grow * KTOT + kt + c4 * 4]);
            *reinterpret_cast<float4*>(&As[r][c4 * 4]) = v;
        }
        #pragma unroll
        for (int it = 0; it < 4; ++it) {
            int flat = it * 256 + tid;
            int k = flat >> 4, c4 = flat & 15;
            float4 v = *reinterpret_cast<const float4*>(&B[(size_t)(kt + k) * ncols + colbase + c4 * 4]);
            *reinterpret_cast<float4*>(&Bs[k][c4 * 4]) = v;
        }
        __syncthreads();
        #pragma unroll 8
        for (int k = 0; k < 64; ++k) {
            float a0 = As[tr * 4 + 0][k];
            float a1 = As[tr * 4 + 1][k];
            float a2 = As[tr * 4 + 2][k];
            float a3 = As[tr * 4 + 3][k];
            float4 bv = *reinterpret_cast<const float4*>(&Bs[k][tc * 4]);
            acc[0][0] += a0 * bv.x; acc[0][1] += a0 * bv.y; acc[0][2] += a0 * bv.z; acc[0][3] += a0 * bv.w;
            acc[1][0] += a1 * bv.x; acc[1][1] += a1 * bv.y; acc[1][2] += a1 * bv.z; acc[1][3] += a1 * bv.w;
            acc[2][0] += a2 * bv.x; acc[2][1] += a2 * bv.y; acc[2][2] += a2 * bv.z; acc[2][3] += a2 * bv.w;
            acc[3][0] += a3 * bv.x; acc[3][1] += a3 * bv.y; acc[3][2] += a3 * bv.z; acc[3][3] += a3 * bv.w;
        }
        __syncthreads();
    }
    #pragma unroll
    for (int i = 0; i < 4; ++i) {
        int row = rowbase + tr * 4 + i;
        if (row < nrows) {
            float4 v = make_float4(acc[i][0], acc[i][1], acc[i][2], acc[i][3]);
            *reinterpret_cast<float4*>(&C[(size_t)row * ncols + colbase + tc * 4]) = v;
        }
    }
}

// ---------------- attention dot products: a_src/a_dst [N,H] ----------------
template<int H>
__global__ __launch_bounds__(256) void attn_dots(const float* __restrict__ h,
                                                 const float* __restrict__ att_src,
                                                 const float* __restrict__ att_dst,
                                                 float* __restrict__ a_src,
                                                 float* __restrict__ a_dst) {
    int n = (blockIdx.x * 256 + threadIdx.x) >> 6;
    int lane = threadIdx.x & 63;
    if (n >= N_NODES) return;
    const float* hp = h + (size_t)n * (H * HID);
    #pragma unroll
    for (int hh = 0; hh < H; ++hh) {
        float v = hp[hh * HID + lane];
        float s = v * att_src[hh * HID + lane];
        float d = v * att_dst[hh * HID + lane];
        #pragma unroll
        for (int off = 32; off; off >>= 1) { s += __shfl_xor(s, off); d += __shfl_xor(d, off); }
        if (lane == 0) { a_src[n * H + hh] = s; a_dst[n * H + hh] = d; }
    }
}

// ---------------- GAT layer-1 aggregation (4 heads x 64 ch), fused bias+relu ----------------
__global__ __launch_bounds__(256) void gat_agg1(const float* __restrict__ h1,
                                                const float* __restrict__ a_src,
                                                const float* __restrict__ a_dst,
                                                const int* __restrict__ rowstart,
                                                const int* __restrict__ srcidx,
                                                const float* __restrict__ b1,
                                                float* __restrict__ out1) {
    int n = (blockIdx.x * 256 + threadIdx.x) >> 6;
    int lane = threadIdx.x & 63;
    if (n >= N_NODES) return;
    int beg = rowstart[n], end = rowstart[n + 1];
    float ad0 = a_dst[n * 4 + 0], ad1 = a_dst[n * 4 + 1];
    float ad2 = a_dst[n * 4 + 2], ad3 = a_dst[n * 4 + 3];

    float m0 = -1e30f, m1 = -1e30f, m2 = -1e30f, m3 = -1e30f;
    for (int i = beg + lane; i < end; i += 64) {
        int s = srcidx[i];
        m0 = fmaxf(m0, lrelu(a_src[s * 4 + 0] + ad0));
        m1 = fmaxf(m1, lrelu(a_src[s * 4 + 1] + ad1));
        m2 = fmaxf(m2, lrelu(a_src[s * 4 + 2] + ad2));
        m3 = fmaxf(m3, lrelu(a_src[s * 4 + 3] + ad3));
    }
    #pragma unroll
    for (int off = 32; off; off >>= 1) {
        m0 = fmaxf(m0, __shfl_xor(m0, off));
        m1 = fmaxf(m1, __shfl_xor(m1, off));
        m2 = fmaxf(m2, __shfl_xor(m2, off));
        m3 = fmaxf(m3, __shfl_xor(m3, off));
    }

    float den0 = 0.f, den1 = 0.f, den2 = 0.f, den3 = 0.f;
    float acc0 = 0.f, acc1 = 0.f, acc2 = 0.f, acc3 = 0.f;
    for (int i = beg; i < end; ++i) {
        int s = srcidx[i];
        float w0 = __expf(lrelu(a_src[s * 4 + 0] + ad0) - m0);
        float w1 = __expf(lrelu(a_src[s * 4 + 1] + ad1) - m1);
        float w2 = __expf(lrelu(a_src[s * 4 + 2] + ad2) - m2);
        float w3 = __expf(lrelu(a_src[s * 4 + 3] + ad3) - m3);
        den0 += w0; den1 += w1; den2 += w2; den3 += w3;
        const float* hp = h1 + (size_t)s * 256;
        acc0 += w0 * hp[lane];
        acc1 += w1 * hp[64 + lane];
        acc2 += w2 * hp[128 + lane];
        acc3 += w3 * hp[192 + lane];
    }
    size_t o = (size_t)n * 256;
    out1[o + lane]       = fmaxf(acc0 / den0 + b1[lane], 0.f);
    out1[o + 64 + lane]  = fmaxf(acc1 / den1 + b1[64 + lane], 0.f);
    out1[o + 128 + lane] = fmaxf(acc2 / den2 + b1[128 + lane], 0.f);
    out1[o + 192 + lane] = fmaxf(acc3 / den3 + b1[192 + lane], 0.f);
}

// ---------------- GAT layer-2 aggregation (1 head) + fused global max pool ----------------
__global__ __launch_bounds__(256) void gat_agg2_pool(const float* __restrict__ h2,
                                                     const float* __restrict__ a_src,
                                                     const float* __restrict__ a_dst,
                                                     const int* __restrict__ rowstart,
                                                     const int* __restrict__ srcidx,
                                                     const float* __restrict__ b2,
                                                     const int* __restrict__ batch,
                                                     unsigned* __restrict__ g) {
    int n = (blockIdx.x * 256 + threadIdx.x) >> 6;
    int lane = threadIdx.x & 63;
    if (n >= N_NODES) return;
    int beg = rowstart[n], end = rowstart[n + 1];
    float ad = a_dst[n];

    float m = -1e30f;
    for (int i = beg + lane; i < end; i += 64)
        m = fmaxf(m, lrelu(a_src[srcidx[i]] + ad));
    #pragma unroll
    for (int off = 32; off; off >>= 1) m = fmaxf(m, __shfl_xor(m, off));

    float den = 0.f, acc = 0.f;
    for (int i = beg; i < end; ++i) {
        int s = srcidx[i];
        float w = __expf(lrelu(a_src[s] + ad) - m);
        den += w;
        acc += w * h2[(size_t)s * 64 + lane];
    }
    float val = fmaxf(acc / den + b2[lane], 0.f);   // relu -> val >= 0, uint order == float order
    atomicMax(&g[(size_t)batch[n] * 64 + lane], __float_as_uint(val));
}

// ---------------- MLP head + log_softmax ----------------
__global__ __launch_bounds__(256) void head_kernel(const float* __restrict__ g,
                                                   const float* __restrict__ w_fc1,
                                                   const float* __restrict__ b_fc1,
                                                   const float* __restrict__ w_fc2,
                                                   const float* __restrict__ b_fc2,
                                                   float* __restrict__ out) {
    __shared__ float gs[64][65];
    __shared__ float hs[64][65];
    int t = threadIdx.x;
    #pragma unroll
    for (int it = 0; it < 16; ++it) {
        int flat = it * 256 + t;
        gs[flat >> 6][flat & 63] = g[flat];
    }
    __syncthreads();
    #pragma unroll
    for (int it = 0; it < 16; ++it) {
        int flat = it * 256 + t;
        int i = flat >> 6, j = flat & 63;
        float s = b_fc1[j];
        #pragma unroll 8
        for (int k = 0; k < 64; ++k) s += gs[i][k] * w_fc1[k * 64 + j];
        hs[i][j] = fmaxf(s, 0.f);
    }
    __syncthreads();
    if (t < 64) {
        float l0 = b_fc2[0], l1 = b_fc2[1];
        #pragma unroll 8
        for (int k = 0; k < 64; ++k) {
            float v = hs[t][k];
            l0 += v * w_fc2[k * 2];
            l1 += v * w_fc2[k * 2 + 1];
        }
        float mx = fmaxf(l0, l1);
        float lse = mx + logf(__expf(l0 - mx) + __expf(l1 - mx));
        out[t * 2]     = l0 - lse;
        out[t * 2 + 1] = l1 - lse;
    }
}

extern "C" void kernel_launch(void* const* d_in, const int* in_sizes, int n_in,
                              void* d_out, int out_size, void* d_ws, size_t ws_size,
                              hipStream_t stream) {
    const float* x        = (const float*)d_in[0];
    const int*   ei       = (const int*)d_in[1];
    const int*   batch    = (const int*)d_in[2];
    const float* W1       = (const float*)d_in[3];
    const float* att_src1 = (const float*)d_in[4];
    const float* att_dst1 = (const float*)d_in[5];
    const float* b1       = (const float*)d_in[6];
    const float* W2       = (const float*)d_in[7];
    const float* att_src2 = (const float*)d_in[8];
    const float* att_dst2 = (const float*)d_in[9];
    const float* b2       = (const float*)d_in[10];
    const float* w_fc1    = (const float*)d_in[11];
    const float* b_fc1    = (const float*)d_in[12];
    const float* w_fc2    = (const float*)d_in[13];
    const float* b_fc2    = (const float*)d_in[14];

    char* ws = (char*)d_ws;
    size_t off = 0;
    auto alloc = [&](size_t bytes) -> char* {
        char* p = ws + off;
        off += (bytes + 255) & ~(size_t)255;
        return p;
    };
    float*    h1       = (float*)alloc((size_t)N_NODES * 256 * 4);
    float*    out1     = (float*)alloc((size_t)N_NODES * 256 * 4);
    float*    h2       = (float*)alloc((size_t)N_NODES * 64 * 4);
    float*    as1      = (float*)alloc((size_t)N_NODES * 4 * 4);
    float*    ad1      = (float*)alloc((size_t)N_NODES * 4 * 4);
    float*    as2      = (float*)alloc((size_t)N_NODES * 4);
    float*    ad2      = (float*)alloc((size_t)N_NODES * 4);
    int*      counts   = (int*)alloc((size_t)N_NODES * 4);
    int*      rowstart = (int*)alloc((size_t)(N_NODES + 4) * 4);
    int*      cursor   = (int*)alloc((size_t)(N_NODES + 4) * 4);
    int*      srcidx   = (int*)alloc((size_t)E_TOT * 4);
    unsigned* g        = (unsigned*)alloc((size_t)N_GRAPHS * HID * 4);

    // init
    zero_kernel<<<(N_NODES + 255) / 256, 256, 0, stream>>>(counts, g);

    // CSR by dst (shared by both layers)
    edge_hist<<<(E_TOT + 255) / 256, 256, 0, stream>>>(ei, counts);
    scan_counts<<<1, 1024, 0, stream>>>(counts, rowstart, cursor);
    edge_scatter<<<(E_TOT + 255) / 256, 256, 0, stream>>>(ei, cursor, srcidx);

    // layer 1
    gemm_tile<128><<<dim3(469, 4), 256, 0, stream>>>(x, W1, h1, N_NODES, 256);
    attn_dots<4><<<7500, 256, 0, stream>>>(h1, att_src1, att_dst1, as1, ad1);
    gat_agg1<<<7500, 256, 0, stream>>>(h1, as1, ad1, rowstart, srcidx, b1, out1);

    // layer 2
    gemm_tile<256><<<dim3(469, 1), 256, 0, stream>>>(out1, W2, h2, N_NODES, 64);
    attn_dots<1><<<7500, 256, 0, stream>>>(h2, att_src2, att_dst2, as2, ad2);
    gat_agg2_pool<<<7500, 256, 0, stream>>>(h2, as2, ad2, rowstart, srcidx, b2, batch, g);

    // head
    head_kernel<<<1, 256, 0, stream>>>((const float*)g, w_fc1, b_fc1, w_fc2, b_fc2, (float*)d_out);
}

// Round 2
// 263.224 us; speedup vs baseline: 1.2620x; 1.2620x over previous
//
#include <hip/hip_runtime.h>
#include <hip/hip_bf16.h>
#include <math.h>

#define N_NODES  30000
#define N_EDGESR 480000
#define E_TOT    (N_EDGESR + N_NODES)
#define N_GRAPHS 64
#define IN_DIM   128
#define HID      64
#define NEG_SLOPE 0.2f

__device__ __forceinline__ float lrelu(float v) { return v > 0.f ? v : NEG_SLOPE * v; }

// ---------------- zero init (counts + pool) ----------------
__global__ void zero_kernel(int* __restrict__ counts, unsigned* __restrict__ g) {
    int t = blockIdx.x * 256 + threadIdx.x;
    if (t < N_NODES) counts[t] = 0;
    if (t < N_GRAPHS * HID) g[t] = 0u;
}

// ---------------- CSR build ----------------
__global__ void edge_hist(const int* __restrict__ ei, int* __restrict__ counts) {
    int e = blockIdx.x * blockDim.x + threadIdx.x;
    if (e >= E_TOT) return;
    int d = (e < N_EDGESR) ? ei[N_EDGESR + e] : (e - N_EDGESR);
    atomicAdd(&counts[d], 1);
}

__global__ __launch_bounds__(1024) void scan_counts(const int* __restrict__ counts,
                                                    int* __restrict__ rowstart,
                                                    int* __restrict__ cursor) {
    __shared__ int bufA[1024];
    __shared__ int bufB[1024];
    const int t = threadIdx.x;
    const int CH = 30;                 // 1024*30 = 30720 >= 30000
    int local[CH];
    int base = t * CH;
    int s = 0;
    #pragma unroll
    for (int i = 0; i < CH; ++i) {
        int idx = base + i;
        int c = (idx < N_NODES) ? counts[idx] : 0;
        local[i] = c; s += c;
    }
    bufA[t] = s;
    __syncthreads();
    int* a = bufA; int* b = bufB;
    for (int off = 1; off < 1024; off <<= 1) {
        int v = a[t] + ((t >= off) ? a[t - off] : 0);
        b[t] = v;
        __syncthreads();
        int* tmp = a; a = b; b = tmp;
    }
    int run = (t == 0) ? 0 : a[t - 1];   // exclusive prefix
    #pragma unroll
    for (int i = 0; i < CH; ++i) {
        int idx = base + i;
        if (idx < N_NODES) { rowstart[idx] = run; cursor[idx] = run; run += local[i]; }
    }
    if (t == 0) rowstart[N_NODES] = E_TOT;
}

__global__ void edge_scatter(const int* __restrict__ ei, int* __restrict__ cursor,
                             int* __restrict__ srcidx) {
    int e = blockIdx.x * blockDim.x + threadIdx.x;
    if (e >= E_TOT) return;
    int s, d;
    if (e < N_EDGESR) { s = ei[e]; d = ei[N_EDGESR + e]; }
    else              { s = d = e - N_EDGESR; }
    int pos = atomicAdd(&cursor[d], 1);
    srcidx[pos] = s;
}

// ---- tiled f32 GEMM with fused attention-dot epilogue ----
// C[nrows,ncols] = A[nrows,KTOT] @ B[KTOT,ncols]; blockIdx.y == head (ncols = H*64).
// a_src[row*H+head] = sum_c C[row, head*64+c] * att_src[head*64+c]  (same for dst)
template<int KTOT>
__global__ __launch_bounds__(256) void gemm_attn(const float* __restrict__ A,
                                                 const float* __restrict__ B,
                                                 float* __restrict__ C,
                                                 int nrows, int ncols,
                                                 const float* __restrict__ att_src,
                                                 const float* __restrict__ att_dst,
                                                 int H,
                                                 float* __restrict__ a_src,
                                                 float* __restrict__ a_dst) {
    __shared__ float As[64][68];   // stride 68: 16B-aligned rows, <=2-way bank conflicts
    __shared__ float Bs[64][64];
    const int tid = threadIdx.x;
    const int rowbase = blockIdx.x * 64;
    const int colbase = blockIdx.y * 64;
    const int tr = tid >> 4;       // 0..15
    const int tc = tid & 15;       // 0..15
    float acc[4][4] = {};

    for (int kt = 0; kt < KTOT; kt += 64) {
        #pragma unroll
        for (int it = 0; it < 4; ++it) {
            int flat = it * 256 + tid;        // 0..1023
            int r = flat >> 4, c4 = flat & 15;
            int grow = rowbase + r; if (grow >= nrows) grow = nrows - 1;
            float4 v = *reinterpret_cast<const float4*>(&A[(size_t)grow * KTOT + kt + c4 * 4]);
            *reinterpret_cast<float4*>(&As[r][c4 * 4]) = v;
        }
        #pragma unroll
        for (int it = 0; it < 4; ++it) {
            int flat = it * 256 + tid;
            int k = flat >> 4, c4 = flat & 15;
            float4 v = *reinterpret_cast<const float4*>(&B[(size_t)(kt + k) * ncols + colbase + c4 * 4]);
            *reinterpret_cast<float4*>(&Bs[k][c4 * 4]) = v;
        }
        __syncthreads();
        #pragma unroll 8
        for (int k = 0; k < 64; ++k) {
            float a0 = As[tr * 4 + 0][k];
            float a1 = As[tr * 4 + 1][k];
            float a2 = As[tr * 4 + 2][k];
            float a3 = As[tr * 4 + 3][k];
            float4 bv = *reinterpret_cast<const float4*>(&Bs[k][tc * 4]);
            acc[0][0] += a0 * bv.x; acc[0][1] += a0 * bv.y; acc[0][2] += a0 * bv.z; acc[0][3] += a0 * bv.w;
            acc[1][0] += a1 * bv.x; acc[1][1] += a1 * bv.y; acc[1][2] += a1 * bv.z; acc[1][3] += a1 * bv.w;
            acc[2][0] += a2 * bv.x; acc[2][1] += a2 * bv.y; acc[2][2] += a2 * bv.z; acc[2][3] += a2 * bv.w;
            acc[3][0] += a3 * bv.x; acc[3][1] += a3 * bv.y; acc[3][2] += a3 * bv.z; acc[3][3] += a3 * bv.w;
        }
        __syncthreads();
    }
    #pragma unroll
    for (int i = 0; i < 4; ++i) {
        int row = rowbase + tr * 4 + i;
        if (row < nrows) {
            float4 v = make_float4(acc[i][0], acc[i][1], acc[i][2], acc[i][3]);
            *reinterpret_cast<float4*>(&C[(size_t)row * ncols + colbase + tc * 4]) = v;
        }
    }
    // fused attention dots
    const int head = blockIdx.y;
    float4 ats = *reinterpret_cast<const float4*>(&att_src[head * 64 + tc * 4]);
    float4 atd = *reinterpret_cast<const float4*>(&att_dst[head * 64 + tc * 4]);
    #pragma unroll
    for (int i = 0; i < 4; ++i) {
        float ps = acc[i][0] * ats.x + acc[i][1] * ats.y + acc[i][2] * ats.z + acc[i][3] * ats.w;
        float pd = acc[i][0] * atd.x + acc[i][1] * atd.y + acc[i][2] * atd.z + acc[i][3] * atd.w;
        #pragma unroll
        for (int off = 1; off < 16; off <<= 1) {
            ps += __shfl_xor(ps, off);
            pd += __shfl_xor(pd, off);
        }
        int row = rowbase + tr * 4 + i;
        if (tc == 0 && row < nrows) {
            a_src[row * H + head] = ps;
            a_dst[row * H + head] = pd;
        }
    }
}

// ---------------- GAT layer-1 aggregation (4 heads x 64 ch), fused bias+relu ----------------
// one wave per node; lane owns channels [4*lane, 4*lane+3] (head = lane>>4)
__global__ __launch_bounds__(256) void gat_agg1(const float* __restrict__ h1,
                                                const float* __restrict__ a_src,
                                                const float* __restrict__ a_dst,
                                                const int* __restrict__ rowstart,
                                                const int* __restrict__ srcidx,
                                                const float* __restrict__ b1,
                                                float* __restrict__ out1) {
    int n = (blockIdx.x * 256 + threadIdx.x) >> 6;
    int lane = threadIdx.x & 63;
    if (n >= N_NODES) return;
    int beg = rowstart[n], end = rowstart[n + 1];
    const int h    = lane & 3;    // head this lane evaluates edge-weights for
    const int slot = lane >> 2;   // edge slot 0..15 within a chunk
    const int myhead = lane >> 4; // head of this lane's output channels
    float ad_h = a_dst[n * 4 + h];

    // pass 1: per-head max over incident edges (slot-parallel)
    float m = -1e30f;
    for (int i = beg + slot; i < end; i += 16) {
        int s = srcidx[i];
        m = fmaxf(m, lrelu(a_src[s * 4 + h] + ad_h));
    }
    #pragma unroll
    for (int off = 4; off < 64; off <<= 1) m = fmaxf(m, __shfl_xor(m, off));
    // lane now holds max for head (lane&3)

    float4 acc = make_float4(0.f, 0.f, 0.f, 0.f);
    float den_part = 0.f;
    int cb = beg;
    for (; cb + 16 <= end; cb += 16) {          // full chunks: static inner loop
        int s = srcidx[cb + slot];
        float w = __expf(lrelu(a_src[s * 4 + h] + ad_h) - m);
        den_part += w;
        #pragma unroll
        for (int j = 0; j < 16; ++j) {
            float wj = __shfl(w, j * 4 + myhead);
            int   sj = __shfl(s, j * 4);
            float4 hv = *reinterpret_cast<const float4*>(&h1[(size_t)sj * 256 + lane * 4]);
            acc.x += wj * hv.x; acc.y += wj * hv.y; acc.z += wj * hv.z; acc.w += wj * hv.w;
        }
    }
    if (cb < end) {                              // tail chunk
        int cnt = end - cb;                      // 1..15
        float w = 0.f; int s = 0;
        if (slot < cnt) {
            s = srcidx[cb + slot];
            w = __expf(lrelu(a_src[s * 4 + h] + ad_h) - m);
            den_part += w;
        }
        for (int j = 0; j < cnt; ++j) {
            float wj = __shfl(w, j * 4 + myhead);
            int   sj = __shfl(s, j * 4);
            float4 hv = *reinterpret_cast<const float4*>(&h1[(size_t)sj * 256 + lane * 4]);
            acc.x += wj * hv.x; acc.y += wj * hv.y; acc.z += wj * hv.z; acc.w += wj * hv.w;
        }
    }
    // reduce denominator per head, then fetch the one for my output head
    #pragma unroll
    for (int off = 4; off < 64; off <<= 1) den_part += __shfl_xor(den_part, off);
    float den = __shfl(den_part, myhead);        // lane 'myhead' holds head==myhead
    float inv = 1.f / den;
    float4 bv = *reinterpret_cast<const float4*>(&b1[lane * 4]);
    float4 o;
    o.x = fmaxf(acc.x * inv + bv.x, 0.f);
    o.y = fmaxf(acc.y * inv + bv.y, 0.f);
    o.z = fmaxf(acc.z * inv + bv.z, 0.f);
    o.w = fmaxf(acc.w * inv + bv.w, 0.f);
    *reinterpret_cast<float4*>(&out1[(size_t)n * 256 + lane * 4]) = o;
}

// ---------------- GAT layer-2 aggregation (1 head) + fused global max pool ----------------
// one wave per node; 4 edges in flight (16 lanes x float4 per edge); block-level pool pre-reduce
__global__ __launch_bounds__(256) void gat_agg2_pool(const float* __restrict__ h2,
                                                     const float* __restrict__ a_src,
                                                     const float* __restrict__ a_dst,
                                                     const int* __restrict__ rowstart,
                                                     const int* __restrict__ srcidx,
                                                     const float* __restrict__ b2,
                                                     const int* __restrict__ batch,
                                                     unsigned* __restrict__ g) {
    __shared__ float sm[4][64];
    const int wid = threadIdx.x >> 6;
    const int lane = threadIdx.x & 63;
    const int n = blockIdx.x * 4 + wid;          // grid covers exactly N_NODES
    const int grp = lane >> 4;                   // edge sub-slot 0..3
    const int cl  = lane & 15;                   // channel quad 0..15
    int beg = rowstart[n], end = rowstart[n + 1];
    float ad = a_dst[n];

    // pass 1: max over edges
    float m = -1e30f;
    for (int i = beg + lane; i < end; i += 64)
        m = fmaxf(m, lrelu(a_src[srcidx[i]] + ad));
    #pragma unroll
    for (int off = 1; off < 64; off <<= 1) m = fmaxf(m, __shfl_xor(m, off));

    float4 acc = make_float4(0.f, 0.f, 0.f, 0.f);
    float den_part = 0.f;
    int cb = beg;
    for (; cb + 16 <= end; cb += 16) {
        float w = 0.f; int s = 0;
        if (lane < 16) {
            s = srcidx[cb + lane];
            w = __expf(lrelu(a_src[s] + ad) - m);
            den_part += w;
        }
        #pragma unroll
        for (int j = 0; j < 16; j += 4) {
            float wj = __shfl(w, j + grp);
            int   sj = __shfl(s, j + grp);
            float4 hv = *reinterpret_cast<const float4*>(&h2[(size_t)sj * 64 + cl * 4]);
            acc.x += wj * hv.x; acc.y += wj * hv.y; acc.z += wj * hv.z; acc.w += wj * hv.w;
        }
    }
    if (cb < end) {
        int cnt = end - cb;
        float w = 0.f; int s = 0;
        if (lane < cnt) {
            s = srcidx[cb + lane];
            w = __expf(lrelu(a_src[s] + ad) - m);
            den_part += w;
        }
        for (int j = 0; j < cnt; j += 4) {
            float wj = __shfl(w, j + grp);
            int   sj = __shfl(s, j + grp);
            if (j + grp < cnt) {
                float4 hv = *reinterpret_cast<const float4*>(&h2[(size_t)sj * 64 + cl * 4]);
                acc.x += wj * hv.x; acc.y += wj * hv.y; acc.z += wj * hv.z; acc.w += wj * hv.w;
            }
        }
    }
    // reduce partial sums across the 4 edge-groups; den across all lanes
    #pragma unroll
    for (int off = 16; off < 64; off <<= 1) {
        acc.x += __shfl_xor(acc.x, off);
        acc.y += __shfl_xor(acc.y, off);
        acc.z += __shfl_xor(acc.z, off);
        acc.w += __shfl_xor(acc.w, off);
    }
    #pragma unroll
    for (int off = 1; off < 64; off <<= 1) den_part += __shfl_xor(den_part, off);
    float inv = 1.f / den_part;
    float4 bv = *reinterpret_cast<const float4*>(&b2[cl * 4]);
    if (lane < 16) {
        float4 val;
        val.x = fmaxf(acc.x * inv + bv.x, 0.f);
        val.y = fmaxf(acc.y * inv + bv.y, 0.f);
        val.z = fmaxf(acc.z * inv + bv.z, 0.f);
        val.w = fmaxf(acc.w * inv + bv.w, 0.f);
        *reinterpret_cast<float4*>(&sm[wid][cl * 4]) = val;
    }
    __syncthreads();
    int b0 = batch[blockIdx.x * 4];
    int b3 = batch[blockIdx.x * 4 + 3];
    if (b0 == b3) {                               // common case: whole block same graph
        if (threadIdx.x < 64) {
            float v = fmaxf(fmaxf(sm[0][threadIdx.x], sm[1][threadIdx.x]),
                            fmaxf(sm[2][threadIdx.x], sm[3][threadIdx.x]));
            atomicMax(&g[b0 * 64 + threadIdx.x], __float_as_uint(v));  // relu => v>=0, uint order ok
        }
    } else {                                      // graph boundary inside block (rare)
        if (lane < 16) {
            int bb = batch[n];
            #pragma unroll
            for (int k = 0; k < 4; ++k)
                atomicMax(&g[bb * 64 + cl * 4 + k], __float_as_uint(sm[wid][cl * 4 + k]));
        }
    }
}

// ---------------- MLP head + log_softmax ----------------
__global__ __launch_bounds__(256) void head_kernel(const float* __restrict__ g,
                                                   const float* __restrict__ w_fc1,
                                                   const float* __restrict__ b_fc1,
                                                   const float* __restrict__ w_fc2,
                                                   const float* __restrict__ b_fc2,
                                                   float* __restrict__ out) {
    __shared__ float gs[64][65];
    __shared__ float hs[64][65];
    int t = threadIdx.x;
    #pragma unroll
    for (int it = 0; it < 16; ++it) {
        int flat = it * 256 + t;
        gs[flat >> 6][flat & 63] = g[flat];
    }
    __syncthreads();
    #pragma unroll
    for (int it = 0; it < 16; ++it) {
        int flat = it * 256 + t;
        int i = flat >> 6, j = flat & 63;
        float s = b_fc1[j];
        #pragma unroll 8
        for (int k = 0; k < 64; ++k) s += gs[i][k] * w_fc1[k * 64 + j];
        hs[i][j] = fmaxf(s, 0.f);
    }
    __syncthreads();
    if (t < 64) {
        float l0 = b_fc2[0], l1 = b_fc2[1];
        #pragma unroll 8
        for (int k = 0; k < 64; ++k) {
            float v = hs[t][k];
            l0 += v * w_fc2[k * 2];
            l1 += v * w_fc2[k * 2 + 1];
        }
        float mx = fmaxf(l0, l1);
        float lse = mx + logf(__expf(l0 - mx) + __expf(l1 - mx));
        out[t * 2]     = l0 - lse;
        out[t * 2 + 1] = l1 - lse;
    }
}

extern "C" void kernel_launch(void* const* d_in, const int* in_sizes, int n_in,
                              void* d_out, int out_size, void* d_ws, size_t ws_size,
                              hipStream_t stream) {
    const float* x        = (const float*)d_in[0];
    const int*   ei       = (const int*)d_in[1];
    const int*   batch    = (const int*)d_in[2];
    const float* W1       = (const float*)d_in[3];
    const float* att_src1 = (const float*)d_in[4];
    const float* att_dst1 = (const float*)d_in[5];
    const float* b1       = (const float*)d_in[6];
    const float* W2       = (const float*)d_in[7];
    const float* att_src2 = (const float*)d_in[8];
    const float* att_dst2 = (const float*)d_in[9];
    const float* b2       = (const float*)d_in[10];
    const float* w_fc1    = (const float*)d_in[11];
    const float* b_fc1    = (const float*)d_in[12];
    const float* w_fc2    = (const float*)d_in[13];
    const float* b_fc2    = (const float*)d_in[14];

    char* ws = (char*)d_ws;
    size_t off = 0;
    auto alloc = [&](size_t bytes) -> char* {
        char* p = ws + off;
        off += (bytes + 255) & ~(size_t)255;
        return p;
    };
    float*    h1       = (float*)alloc((size_t)N_NODES * 256 * 4);
    float*    out1     = (float*)alloc((size_t)N_NODES * 256 * 4);
    float*    h2       = (float*)alloc((size_t)N_NODES * 64 * 4);
    float*    as1      = (float*)alloc((size_t)N_NODES * 4 * 4);
    float*    ad1      = (float*)alloc((size_t)N_NODES * 4 * 4);
    float*    as2      = (float*)alloc((size_t)N_NODES * 4);
    float*    ad2      = (float*)alloc((size_t)N_NODES * 4);
    int*      counts   = (int*)alloc((size_t)N_NODES * 4);
    int*      rowstart = (int*)alloc((size_t)(N_NODES + 4) * 4);
    int*      cursor   = (int*)alloc((size_t)(N_NODES + 4) * 4);
    int*      srcidx   = (int*)alloc((size_t)E_TOT * 4);
    unsigned* g        = (unsigned*)alloc((size_t)N_GRAPHS * HID * 4);

    // init
    zero_kernel<<<(N_NODES + 255) / 256, 256, 0, stream>>>(counts, g);

    // CSR by dst (shared by both layers)
    edge_hist<<<(E_TOT + 255) / 256, 256, 0, stream>>>(ei, counts);
    scan_counts<<<1, 1024, 0, stream>>>(counts, rowstart, cursor);
    edge_scatter<<<(E_TOT + 255) / 256, 256, 0, stream>>>(ei, cursor, srcidx);

    // layer 1 (GEMM + fused attn dots)
    gemm_attn<128><<<dim3(469, 4), 256, 0, stream>>>(x, W1, h1, N_NODES, 256,
                                                     att_src1, att_dst1, 4, as1, ad1);
    gat_agg1<<<7500, 256, 0, stream>>>(h1, as1, ad1, rowstart, srcidx, b1, out1);

    // layer 2
    gemm_attn<256><<<dim3(469, 1), 256, 0, stream>>>(out1, W2, h2, N_NODES, 64,
                                                     att_src2, att_dst2, 1, as2, ad2);
    gat_agg2_pool<<<7500, 256, 0, stream>>>(h2, as2, ad2, rowstart, srcidx, b2, batch, g);

    // head
    head_kernel<<<1, 256, 0, stream>>>((const float*)g, w_fc1, b_fc1, w_fc2, b_fc2, (float*)d_out);
}

// Round 3
// 242.973 us; speedup vs baseline: 1.3671x; 1.0833x over previous
//
#include <hip/hip_runtime.h>
#include <hip/hip_bf16.h>
#include <math.h>

#define N_NODES  30000
#define N_EDGESR 480000
#define E_TOT    (N_EDGESR + N_NODES)
#define N_GRAPHS 64
#define IN_DIM   128
#define HID      64
#define NEG_SLOPE 0.2f

__device__ __forceinline__ float lrelu(float v) { return v > 0.f ? v : NEG_SLOPE * v; }
__device__ __forceinline__ float bf2f(unsigned short u) { return __uint_as_float((unsigned)u << 16); }

// ---------------- zero init (counts + pool) ----------------
__global__ void zero_kernel(int* __restrict__ counts, unsigned* __restrict__ g) {
    int t = blockIdx.x * 256 + threadIdx.x;
    if (t < N_NODES) counts[t] = 0;
    if (t < N_GRAPHS * HID) g[t] = 0u;
}

// ---------------- CSR build ----------------
__global__ void edge_hist(const int* __restrict__ ei, int* __restrict__ counts) {
    int e = blockIdx.x * blockDim.x + threadIdx.x;
    if (e >= E_TOT) return;
    int d = (e < N_EDGESR) ? ei[N_EDGESR + e] : (e - N_EDGESR);
    atomicAdd(&counts[d], 1);
}

__global__ __launch_bounds__(1024) void scan_counts(const int* __restrict__ counts,
                                                    int* __restrict__ rowstart,
                                                    int* __restrict__ cursor) {
    __shared__ int bufA[1024];
    __shared__ int bufB[1024];
    const int t = threadIdx.x;
    const int CH = 30;                 // 1024*30 = 30720 >= 30000
    int local[CH];
    int base = t * CH;
    int s = 0;
    #pragma unroll
    for (int i = 0; i < CH; ++i) {
        int idx = base + i;
        int c = (idx < N_NODES) ? counts[idx] : 0;
        local[i] = c; s += c;
    }
    bufA[t] = s;
    __syncthreads();
    int* a = bufA; int* b = bufB;
    for (int off = 1; off < 1024; off <<= 1) {
        int v = a[t] + ((t >= off) ? a[t - off] : 0);
        b[t] = v;
        __syncthreads();
        int* tmp = a; a = b; b = tmp;
    }
    int run = (t == 0) ? 0 : a[t - 1];   // exclusive prefix
    #pragma unroll
    for (int i = 0; i < CH; ++i) {
        int idx = base + i;
        if (idx < N_NODES) { rowstart[idx] = run; cursor[idx] = run; run += local[i]; }
    }
    if (t == 0) rowstart[N_NODES] = E_TOT;
}

__global__ void edge_scatter(const int* __restrict__ ei, int* __restrict__ cursor,
                             int* __restrict__ srcidx) {
    int e = blockIdx.x * blockDim.x + threadIdx.x;
    if (e >= E_TOT) return;
    int s, d;
    if (e < N_EDGESR) { s = ei[e]; d = ei[N_EDGESR + e]; }
    else              { s = d = e - N_EDGESR; }
    int pos = atomicAdd(&cursor[d], 1);
    srcidx[pos] = s;
}

// ---- tiled f32 GEMM with fused attention-dot epilogue ----
// C[nrows,ncols] = A[nrows,KTOT] @ B[KTOT,ncols]; blockIdx.y == head (ncols = H*64).
// If WB16, C is written as bf16 (__hip_bfloat16*), else f32.
// a_src[row*H+head] = sum_c C[row, head*64+c] * att_src[head*64+c]  (same for dst)
template<int KTOT, bool WB16>
__global__ __launch_bounds__(256) void gemm_attn(const float* __restrict__ A,
                                                 const float* __restrict__ B,
                                                 void* __restrict__ Cv,
                                                 int nrows, int ncols,
                                                 const float* __restrict__ att_src,
                                                 const float* __restrict__ att_dst,
                                                 int H,
                                                 float* __restrict__ a_src,
                                                 float* __restrict__ a_dst) {
    __shared__ float As[64][68];   // stride 68: 16B-aligned rows, <=2-way bank conflicts
    __shared__ float Bs[64][64];
    const int tid = threadIdx.x;
    const int rowbase = blockIdx.x * 64;
    const int colbase = blockIdx.y * 64;
    const int tr = tid >> 4;       // 0..15
    const int tc = tid & 15;       // 0..15
    float acc[4][4] = {};

    for (int kt = 0; kt < KTOT; kt += 64) {
        #pragma unroll
        for (int it = 0; it < 4; ++it) {
            int flat = it * 256 + tid;        // 0..1023
            int r = flat >> 4, c4 = flat & 15;
            int grow = rowbase + r; if (grow >= nrows) grow = nrows - 1;
            float4 v = *reinterpret_cast<const float4*>(&A[(size_t)grow * KTOT + kt + c4 * 4]);
            *reinterpret_cast<float4*>(&As[r][c4 * 4]) = v;
        }
        #pragma unroll
        for (int it = 0; it < 4; ++it) {
            int flat = it * 256 + tid;
            int k = flat >> 4, c4 = flat & 15;
            float4 v = *reinterpret_cast<const float4*>(&B[(size_t)(kt + k) * ncols + colbase + c4 * 4]);
            *reinterpret_cast<float4*>(&Bs[k][c4 * 4]) = v;
        }
        __syncthreads();
        #pragma unroll 8
        for (int k = 0; k < 64; ++k) {
            float a0 = As[tr * 4 + 0][k];
            float a1 = As[tr * 4 + 1][k];
            float a2 = As[tr * 4 + 2][k];
            float a3 = As[tr * 4 + 3][k];
            float4 bv = *reinterpret_cast<const float4*>(&Bs[k][tc * 4]);
            acc[0][0] += a0 * bv.x; acc[0][1] += a0 * bv.y; acc[0][2] += a0 * bv.z; acc[0][3] += a0 * bv.w;
            acc[1][0] += a1 * bv.x; acc[1][1] += a1 * bv.y; acc[1][2] += a1 * bv.z; acc[1][3] += a1 * bv.w;
            acc[2][0] += a2 * bv.x; acc[2][1] += a2 * bv.y; acc[2][2] += a2 * bv.z; acc[2][3] += a2 * bv.w;
            acc[3][0] += a3 * bv.x; acc[3][1] += a3 * bv.y; acc[3][2] += a3 * bv.z; acc[3][3] += a3 * bv.w;
        }
        __syncthreads();
    }
    #pragma unroll
    for (int i = 0; i < 4; ++i) {
        int row = rowbase + tr * 4 + i;
        if (row < nrows) {
            if (WB16) {
                __hip_bfloat16* C = (__hip_bfloat16*)Cv;
                ushort4 v;
                v.x = __bfloat16_as_ushort(__float2bfloat16(acc[i][0]));
                v.y = __bfloat16_as_ushort(__float2bfloat16(acc[i][1]));
                v.z = __bfloat16_as_ushort(__float2bfloat16(acc[i][2]));
                v.w = __bfloat16_as_ushort(__float2bfloat16(acc[i][3]));
                *reinterpret_cast<ushort4*>(&C[(size_t)row * ncols + colbase + tc * 4]) = v;
            } else {
                float* C = (float*)Cv;
                float4 v = make_float4(acc[i][0], acc[i][1], acc[i][2], acc[i][3]);
                *reinterpret_cast<float4*>(&C[(size_t)row * ncols + colbase + tc * 4]) = v;
            }
        }
    }
    // fused attention dots (from f32 accumulators — no precision loss)
    const int head = blockIdx.y;
    float4 ats = *reinterpret_cast<const float4*>(&att_src[head * 64 + tc * 4]);
    float4 atd = *reinterpret_cast<const float4*>(&att_dst[head * 64 + tc * 4]);
    #pragma unroll
    for (int i = 0; i < 4; ++i) {
        float ps = acc[i][0] * ats.x + acc[i][1] * ats.y + acc[i][2] * ats.z + acc[i][3] * ats.w;
        float pd = acc[i][0] * atd.x + acc[i][1] * atd.y + acc[i][2] * atd.z + acc[i][3] * atd.w;
        #pragma unroll
        for (int off = 1; off < 16; off <<= 1) {
            ps += __shfl_xor(ps, off);
            pd += __shfl_xor(pd, off);
        }
        int row = rowbase + tr * 4 + i;
        if (tc == 0 && row < nrows) {
            a_src[row * H + head] = ps;
            a_dst[row * H + head] = pd;
        }
    }
}

// ---------------- GAT layer-1 aggregation (4 heads x 64 ch), fused bias+relu ----------------
// one wave per node; lane owns channels [4*lane, 4*lane+3] (head = lane>>4); h1 is bf16
__global__ __launch_bounds__(256) void gat_agg1(const __hip_bfloat16* __restrict__ h1,
                                                const float* __restrict__ a_src,
                                                const float* __restrict__ a_dst,
                                                const int* __restrict__ rowstart,
                                                const int* __restrict__ srcidx,
                                                const float* __restrict__ b1,
                                                float* __restrict__ out1) {
    int n = (blockIdx.x * 256 + threadIdx.x) >> 6;
    int lane = threadIdx.x & 63;
    if (n >= N_NODES) return;
    int beg = rowstart[n], end = rowstart[n + 1];
    const int h    = lane & 3;    // head this lane evaluates edge-weights for
    const int slot = lane >> 2;   // edge slot 0..15 within a chunk
    const int myhead = lane >> 4; // head of this lane's output channels
    float ad_h = a_dst[n * 4 + h];

    // pass 1: per-head max over incident edges (slot-parallel)
    float m = -1e30f;
    for (int i = beg + slot; i < end; i += 16) {
        int s = srcidx[i];
        m = fmaxf(m, lrelu(a_src[s * 4 + h] + ad_h));
    }
    #pragma unroll
    for (int off = 4; off < 64; off <<= 1) m = fmaxf(m, __shfl_xor(m, off));
    // lane now holds max for head (lane&3)

    float4 acc = make_float4(0.f, 0.f, 0.f, 0.f);
    float den_part = 0.f;
    int cb = beg;
    for (; cb + 16 <= end; cb += 16) {          // full chunks: static inner loop
        int s = srcidx[cb + slot];
        float w = __expf(lrelu(a_src[s * 4 + h] + ad_h) - m);
        den_part += w;
        #pragma unroll
        for (int j = 0; j < 16; ++j) {
            float wj = __shfl(w, j * 4 + myhead);
            int   sj = __shfl(s, j * 4);
            ushort4 hv = *reinterpret_cast<const ushort4*>(&h1[(size_t)sj * 256 + lane * 4]);
            acc.x += wj * bf2f(hv.x); acc.y += wj * bf2f(hv.y);
            acc.z += wj * bf2f(hv.z); acc.w += wj * bf2f(hv.w);
        }
    }
    if (cb < end) {                              // tail chunk
        int cnt = end - cb;                      // 1..15
        float w = 0.f; int s = 0;
        if (slot < cnt) {
            s = srcidx[cb + slot];
            w = __expf(lrelu(a_src[s * 4 + h] + ad_h) - m);
            den_part += w;
        }
        for (int j = 0; j < cnt; ++j) {
            float wj = __shfl(w, j * 4 + myhead);
            int   sj = __shfl(s, j * 4);
            ushort4 hv = *reinterpret_cast<const ushort4*>(&h1[(size_t)sj * 256 + lane * 4]);
            acc.x += wj * bf2f(hv.x); acc.y += wj * bf2f(hv.y);
            acc.z += wj * bf2f(hv.z); acc.w += wj * bf2f(hv.w);
        }
    }
    // reduce denominator per head, then fetch the one for my output head
    #pragma unroll
    for (int off = 4; off < 64; off <<= 1) den_part += __shfl_xor(den_part, off);
    float den = __shfl(den_part, myhead);        // lane 'myhead' holds head==myhead
    float inv = 1.f / den;
    float4 bv = *reinterpret_cast<const float4*>(&b1[lane * 4]);
    float4 o;
    o.x = fmaxf(acc.x * inv + bv.x, 0.f);
    o.y = fmaxf(acc.y * inv + bv.y, 0.f);
    o.z = fmaxf(acc.z * inv + bv.z, 0.f);
    o.w = fmaxf(acc.w * inv + bv.w, 0.f);
    *reinterpret_cast<float4*>(&out1[(size_t)n * 256 + lane * 4]) = o;
}

// ---------------- GAT layer-2 aggregation (1 head) + fused global max pool ----------------
// one wave per node; 4 edges in flight (16 lanes x bf16x4 per edge); block-level pool pre-reduce
__global__ __launch_bounds__(256) void gat_agg2_pool(const __hip_bfloat16* __restrict__ h2,
                                                     const float* __restrict__ a_src,
                                                     const float* __restrict__ a_dst,
                                                     const int* __restrict__ rowstart,
                                                     const int* __restrict__ srcidx,
                                                     const float* __restrict__ b2,
                                                     const int* __restrict__ batch,
                                                     unsigned* __restrict__ g) {
    __shared__ float sm[4][64];
    const int wid = threadIdx.x >> 6;
    const int lane = threadIdx.x & 63;
    const int n = blockIdx.x * 4 + wid;          // grid covers exactly N_NODES
    const int grp = lane >> 4;                   // edge sub-slot 0..3
    const int cl  = lane & 15;                   // channel quad 0..15
    int beg = rowstart[n], end = rowstart[n + 1];
    float ad = a_dst[n];

    // pass 1: max over edges
    float m = -1e30f;
    for (int i = beg + lane; i < end; i += 64)
        m = fmaxf(m, lrelu(a_src[srcidx[i]] + ad));
    #pragma unroll
    for (int off = 1; off < 64; off <<= 1) m = fmaxf(m, __shfl_xor(m, off));

    float4 acc = make_float4(0.f, 0.f, 0.f, 0.f);
    float den_part = 0.f;
    int cb = beg;
    for (; cb + 16 <= end; cb += 16) {
        float w = 0.f; int s = 0;
        if (lane < 16) {
            s = srcidx[cb + lane];
            w = __expf(lrelu(a_src[s] + ad) - m);
            den_part += w;
        }
        #pragma unroll
        for (int j = 0; j < 16; j += 4) {
            float wj = __shfl(w, j + grp);
            int   sj = __shfl(s, j + grp);
            ushort4 hv = *reinterpret_cast<const ushort4*>(&h2[(size_t)sj * 64 + cl * 4]);
            acc.x += wj * bf2f(hv.x); acc.y += wj * bf2f(hv.y);
            acc.z += wj * bf2f(hv.z); acc.w += wj * bf2f(hv.w);
        }
    }
    if (cb < end) {
        int cnt = end - cb;
        float w = 0.f; int s = 0;
        if (lane < cnt) {
            s = srcidx[cb + lane];
            w = __expf(lrelu(a_src[s] + ad) - m);
            den_part += w;
        }
        for (int j = 0; j < cnt; j += 4) {
            float wj = __shfl(w, j + grp);
            int   sj = __shfl(s, j + grp);
            if (j + grp < cnt) {
                ushort4 hv = *reinterpret_cast<const ushort4*>(&h2[(size_t)sj * 64 + cl * 4]);
                acc.x += wj * bf2f(hv.x); acc.y += wj * bf2f(hv.y);
                acc.z += wj * bf2f(hv.z); acc.w += wj * bf2f(hv.w);
            }
        }
    }
    // reduce partial sums across the 4 edge-groups; den across all lanes
    #pragma unroll
    for (int off = 16; off < 64; off <<= 1) {
        acc.x += __shfl_xor(acc.x, off);
        acc.y += __shfl_xor(acc.y, off);
        acc.z += __shfl_xor(acc.z, off);
        acc.w += __shfl_xor(acc.w, off);
    }
    #pragma unroll
    for (int off = 1; off < 64; off <<= 1) den_part += __shfl_xor(den_part, off);
    float inv = 1.f / den_part;
    float4 bv = *reinterpret_cast<const float4*>(&b2[cl * 4]);
    if (lane < 16) {
        float4 val;
        val.x = fmaxf(acc.x * inv + bv.x, 0.f);
        val.y = fmaxf(acc.y * inv + bv.y, 0.f);
        val.z = fmaxf(acc.z * inv + bv.z, 0.f);
        val.w = fmaxf(acc.w * inv + bv.w, 0.f);
        *reinterpret_cast<float4*>(&sm[wid][cl * 4]) = val;
    }
    __syncthreads();
    int b0 = batch[blockIdx.x * 4];
    int b3 = batch[blockIdx.x * 4 + 3];
    if (b0 == b3) {                               // common case: whole block same graph
        if (threadIdx.x < 64) {
            float v = fmaxf(fmaxf(sm[0][threadIdx.x], sm[1][threadIdx.x]),
                            fmaxf(sm[2][threadIdx.x], sm[3][threadIdx.x]));
            atomicMax(&g[b0 * 64 + threadIdx.x], __float_as_uint(v));  // relu => v>=0, uint order ok
        }
    } else {                                      // graph boundary inside block (rare)
        if (lane < 16) {
            int bb = batch[n];
            #pragma unroll
            for (int k = 0; k < 4; ++k)
                atomicMax(&g[bb * 64 + cl * 4 + k], __float_as_uint(sm[wid][cl * 4 + k]));
        }
    }
}

// ---------------- MLP head + log_softmax ----------------
__global__ __launch_bounds__(256) void head_kernel(const float* __restrict__ g,
                                                   const float* __restrict__ w_fc1,
                                                   const float* __restrict__ b_fc1,
                                                   const float* __restrict__ w_fc2,
                                                   const float* __restrict__ b_fc2,
                                                   float* __restrict__ out) {
    __shared__ float gs[64][65];
    __shared__ float hs[64][65];
    int t = threadIdx.x;
    #pragma unroll
    for (int it = 0; it < 16; ++it) {
        int flat = it * 256 + t;
        gs[flat >> 6][flat & 63] = g[flat];
    }
    __syncthreads();
    #pragma unroll
    for (int it = 0; it < 16; ++it) {
        int flat = it * 256 + t;
        int i = flat >> 6, j = flat & 63;
        float s = b_fc1[j];
        #pragma unroll 8
        for (int k = 0; k < 64; ++k) s += gs[i][k] * w_fc1[k * 64 + j];
        hs[i][j] = fmaxf(s, 0.f);
    }
    __syncthreads();
    if (t < 64) {
        float l0 = b_fc2[0], l1 = b_fc2[1];
        #pragma unroll 8
        for (int k = 0; k < 64; ++k) {
            float v = hs[t][k];
            l0 += v * w_fc2[k * 2];
            l1 += v * w_fc2[k * 2 + 1];
        }
        float mx = fmaxf(l0, l1);
        float lse = mx + logf(__expf(l0 - mx) + __expf(l1 - mx));
        out[t * 2]     = l0 - lse;
        out[t * 2 + 1] = l1 - lse;
    }
}

extern "C" void kernel_launch(void* const* d_in, const int* in_sizes, int n_in,
                              void* d_out, int out_size, void* d_ws, size_t ws_size,
                              hipStream_t stream) {
    const float* x        = (const float*)d_in[0];
    const int*   ei       = (const int*)d_in[1];
    const int*   batch    = (const int*)d_in[2];
    const float* W1       = (const float*)d_in[3];
    const float* att_src1 = (const float*)d_in[4];
    const float* att_dst1 = (const float*)d_in[5];
    const float* b1       = (const float*)d_in[6];
    const float* W2       = (const float*)d_in[7];
    const float* att_src2 = (const float*)d_in[8];
    const float* att_dst2 = (const float*)d_in[9];
    const float* b2       = (const float*)d_in[10];
    const float* w_fc1    = (const float*)d_in[11];
    const float* b_fc1    = (const float*)d_in[12];
    const float* w_fc2    = (const float*)d_in[13];
    const float* b_fc2    = (const float*)d_in[14];

    char* ws = (char*)d_ws;
    size_t off = 0;
    auto alloc = [&](size_t bytes) -> char* {
        char* p = ws + off;
        off += (bytes + 255) & ~(size_t)255;
        return p;
    };
    __hip_bfloat16* h1   = (__hip_bfloat16*)alloc((size_t)N_NODES * 256 * 2);
    float*    out1       = (float*)alloc((size_t)N_NODES * 256 * 4);
    __hip_bfloat16* h2   = (__hip_bfloat16*)alloc((size_t)N_NODES * 64 * 2);
    float*    as1        = (float*)alloc((size_t)N_NODES * 4 * 4);
    float*    ad1        = (float*)alloc((size_t)N_NODES * 4 * 4);
    float*    as2        = (float*)alloc((size_t)N_NODES * 4);
    float*    ad2        = (float*)alloc((size_t)N_NODES * 4);
    int*      counts     = (int*)alloc((size_t)N_NODES * 4);
    int*      rowstart   = (int*)alloc((size_t)(N_NODES + 4) * 4);
    int*      cursor     = (int*)alloc((size_t)(N_NODES + 4) * 4);
    int*      srcidx     = (int*)alloc((size_t)E_TOT * 4);
    unsigned* g          = (unsigned*)alloc((size_t)N_GRAPHS * HID * 4);

    // init
    zero_kernel<<<(N_NODES + 255) / 256, 256, 0, stream>>>(counts, g);

    // CSR by dst (shared by both layers)
    edge_hist<<<(E_TOT + 255) / 256, 256, 0, stream>>>(ei, counts);
    scan_counts<<<1, 1024, 0, stream>>>(counts, rowstart, cursor);
    edge_scatter<<<(E_TOT + 255) / 256, 256, 0, stream>>>(ei, cursor, srcidx);

    // layer 1 (GEMM + fused attn dots, bf16 h1)
    gemm_attn<128, true><<<dim3(469, 4), 256, 0, stream>>>(x, W1, (void*)h1, N_NODES, 256,
                                                           att_src1, att_dst1, 4, as1, ad1);
    gat_agg1<<<7500, 256, 0, stream>>>(h1, as1, ad1, rowstart, srcidx, b1, out1);

    // layer 2 (bf16 h2)
    gemm_attn<256, true><<<dim3(469, 1), 256, 0, stream>>>(out1, W2, (void*)h2, N_NODES, 64,
                                                           att_src2, att_dst2, 1, as2, ad2);
    gat_agg2_pool<<<7500, 256, 0, stream>>>(h2, as2, ad2, rowstart, srcidx, b2, batch, g);

    // head
    head_kernel<<<1, 256, 0, stream>>>((const float*)g, w_fc1, b_fc1, w_fc2, b_fc2, (float*)d_out);
}

// Round 4
// 199.386 us; speedup vs baseline: 1.6660x; 1.2186x over previous
//
#include <hip/hip_runtime.h>
#include <hip/hip_bf16.h>
#include <math.h>

#define N_NODES  30000
#define N_EDGESR 480000
#define E_TOT    (N_EDGESR + N_NODES)
#define N_GRAPHS 64
#define IN_DIM   128
#define HID      64
#define NEG_SLOPE 0.2f

typedef __attribute__((ext_vector_type(8))) short bf16x8;
typedef __attribute__((ext_vector_type(4))) float f32x4;

__device__ __forceinline__ float lrelu(float v) { return v > 0.f ? v : NEG_SLOPE * v; }
__device__ __forceinline__ float bf2f(unsigned short u) { return __uint_as_float((unsigned)u << 16); }
__device__ __forceinline__ unsigned short f2bf(float f) {
    return __bfloat16_as_ushort(__float2bfloat16(f));
}

// ---------------- zero init (counts + pool) ----------------
__global__ void zero_kernel(int* __restrict__ counts, unsigned* __restrict__ g) {
    int t = blockIdx.x * 256 + threadIdx.x;
    if (t < N_NODES) counts[t] = 0;
    if (t < N_GRAPHS * HID) g[t] = 0u;
}

// ---------------- bf16 conversions ----------------
__global__ void conv_x_kernel(const float* __restrict__ x, unsigned short* __restrict__ xb) {
    int i = (blockIdx.x * 256 + threadIdx.x) * 4;      // grid covers exactly N_NODES*128
    float4 v = *reinterpret_cast<const float4*>(x + i);
    ushort4 o;
    o.x = f2bf(v.x); o.y = f2bf(v.y); o.z = f2bf(v.z); o.w = f2bf(v.w);
    *reinterpret_cast<ushort4*>(xb + i) = o;
}

// W1 [128][256] -> w1t bf16 [256][128];  W2 [256][64] -> w2t bf16 [64][256]
__global__ void conv_w_kernel(const float* __restrict__ W1, const float* __restrict__ W2,
                              unsigned short* __restrict__ w1t, unsigned short* __restrict__ w2t) {
    int id = blockIdx.x * 256 + threadIdx.x;           // 0 .. 49151
    if (id < 128 * 256) {
        int k = id >> 8, n = id & 255;
        w1t[n * 128 + k] = f2bf(W1[id]);
    } else {
        int id2 = id - 128 * 256;                      // < 16384
        int k = id2 >> 6, n = id2 & 63;
        w2t[n * 256 + k] = f2bf(W2[id2]);
    }
}

// ---------------- CSR build ----------------
__global__ void edge_hist(const int* __restrict__ ei, int* __restrict__ counts) {
    int e = blockIdx.x * blockDim.x + threadIdx.x;
    if (e >= E_TOT) return;
    int d = (e < N_EDGESR) ? ei[N_EDGESR + e] : (e - N_EDGESR);
    atomicAdd(&counts[d], 1);
}

__global__ __launch_bounds__(1024) void scan_counts(const int* __restrict__ counts,
                                                    int* __restrict__ rowstart,
                                                    int* __restrict__ cursor) {
    __shared__ int bufA[1024];
    __shared__ int bufB[1024];
    const int t = threadIdx.x;
    const int CH = 30;
    int local[CH];
    int base = t * CH;
    int s = 0;
    #pragma unroll
    for (int i = 0; i < CH; ++i) {
        int idx = base + i;
        int c = (idx < N_NODES) ? counts[idx] : 0;
        local[i] = c; s += c;
    }
    bufA[t] = s;
    __syncthreads();
    int* a = bufA; int* b = bufB;
    for (int off = 1; off < 1024; off <<= 1) {
        int v = a[t] + ((t >= off) ? a[t - off] : 0);
        b[t] = v;
        __syncthreads();
        int* tmp = a; a = b; b = tmp;
    }
    int run = (t == 0) ? 0 : a[t - 1];
    #pragma unroll
    for (int i = 0; i < CH; ++i) {
        int idx = base + i;
        if (idx < N_NODES) { rowstart[idx] = run; cursor[idx] = run; run += local[i]; }
    }
    if (t == 0) rowstart[N_NODES] = E_TOT;
}

__global__ void edge_scatter(const int* __restrict__ ei, int* __restrict__ cursor,
                             int* __restrict__ srcidx) {
    int e = blockIdx.x * blockDim.x + threadIdx.x;
    if (e >= E_TOT) return;
    int s, d;
    if (e < N_EDGESR) { s = ei[e]; d = ei[N_EDGESR + e]; }
    else              { s = d = e - N_EDGESR; }
    int pos = atomicAdd(&cursor[d], 1);
    srcidx[pos] = s;
}

// ---- MFMA GEMM1: h1[30000,256] = xb[30000,128] @ W1 (w1t is [256][128] bf16) ----
// block = 64 rows; wave w = head w (cols w*64..+63). Fused attn-dot epilogue.
// mfma(bfrag, afrag, acc): C row = lane&15 (A free idx), col = (lane>>4)*4+reg (B free idx).
__global__ __launch_bounds__(256) void mfma_gemm1(const unsigned short* __restrict__ xb,
                                                  const unsigned short* __restrict__ w1t,
                                                  unsigned short* __restrict__ h1,
                                                  const float* __restrict__ att_src,
                                                  const float* __restrict__ att_dst,
                                                  float* __restrict__ a_src,
                                                  float* __restrict__ a_dst) {
    __shared__ __align__(16) unsigned short As[64 * 128];  // 16 KB, row stride 256 B, XOR-swizzled
    const int tid = threadIdx.x;
    const int w = tid >> 6;
    const int l = tid & 63;
    const int rowbase = blockIdx.x * 64;
    char* Ab = (char*)As;

    #pragma unroll
    for (int i = 0; i < 4; ++i) {
        int flat = i * 256 + tid;            // 16B-chunk id 0..1023
        int r = flat >> 4;                   // row 0..63
        int cb = (flat & 15) * 16;           // byte col
        int gr = rowbase + r; if (gr >= N_NODES) gr = N_NODES - 1;
        int4 v = *reinterpret_cast<const int4*>(xb + (size_t)gr * 128 + (cb >> 1));
        *reinterpret_cast<int4*>(Ab + r * 256 + (cb ^ ((r & 7) << 4))) = v;
    }
    __syncthreads();

    const int lm = l & 15, lh = l >> 4;
    f32x4 acc[4][4];
    #pragma unroll
    for (int rt = 0; rt < 4; ++rt)
        #pragma unroll
        for (int ct = 0; ct < 4; ++ct)
            acc[rt][ct] = (f32x4){0.f, 0.f, 0.f, 0.f};

    #pragma unroll
    for (int s = 0; s < 4; ++s) {
        bf16x8 bfr[4], afr[4];
        #pragma unroll
        for (int ct = 0; ct < 4; ++ct) {
            int n = w * 64 + ct * 16 + lm;
            bfr[ct] = *reinterpret_cast<const bf16x8*>(w1t + n * 128 + s * 32 + lh * 8);
        }
        #pragma unroll
        for (int rt = 0; rt < 4; ++rt) {
            int row = rt * 16 + lm;
            int cb = s * 64 + lh * 16;
            afr[rt] = *reinterpret_cast<const bf16x8*>(Ab + row * 256 + (cb ^ ((row & 7) << 4)));
        }
        #pragma unroll
        for (int rt = 0; rt < 4; ++rt)
            #pragma unroll
            for (int ct = 0; ct < 4; ++ct)
                acc[rt][ct] = __builtin_amdgcn_mfma_f32_16x16x32_bf16(bfr[ct], afr[rt], acc[rt][ct], 0, 0, 0);
    }

    // epilogue: bf16 C write (8B packed) + fused attention dots for head w
    #pragma unroll
    for (int rt = 0; rt < 4; ++rt) {
        int row = rowbase + rt * 16 + lm;
        float ps = 0.f, pd = 0.f;
        #pragma unroll
        for (int ct = 0; ct < 4; ++ct) {
            int col = w * 64 + ct * 16 + lh * 4;
            if (row < N_NODES) {
                ushort4 o;
                o.x = f2bf(acc[rt][ct][0]); o.y = f2bf(acc[rt][ct][1]);
                o.z = f2bf(acc[rt][ct][2]); o.w = f2bf(acc[rt][ct][3]);
                *reinterpret_cast<ushort4*>(h1 + (size_t)row * 256 + col) = o;
            }
            #pragma unroll
            for (int q = 0; q < 4; ++q) {
                ps += acc[rt][ct][q] * att_src[col + q];
                pd += acc[rt][ct][q] * att_dst[col + q];
            }
        }
        ps += __shfl_xor(ps, 16); ps += __shfl_xor(ps, 32);
        pd += __shfl_xor(pd, 16); pd += __shfl_xor(pd, 32);
        if (lh == 0 && row < N_NODES) {
            a_src[row * 4 + w] = ps;
            a_dst[row * 4 + w] = pd;
        }
    }
}

// ---- MFMA GEMM2: h2[30000,64] = out1b[30000,256] @ W2 (w2t is [64][256] bf16) ----
// block = 64 rows; wave w = col-tile w (cols w*16..+15), K = 256 (8 steps).
__global__ __launch_bounds__(256) void mfma_gemm2(const unsigned short* __restrict__ a1b,
                                                  const unsigned short* __restrict__ w2t,
                                                  unsigned short* __restrict__ h2,
                                                  const float* __restrict__ att_src,
                                                  const float* __restrict__ att_dst,
                                                  float* __restrict__ a_src,
                                                  float* __restrict__ a_dst) {
    __shared__ __align__(16) unsigned short As[64 * 256];  // 32 KB, row stride 512 B, swizzled
    __shared__ float ps_s[4][64], pd_s[4][64];
    const int tid = threadIdx.x;
    const int w = tid >> 6, l = tid & 63;
    const int rowbase = blockIdx.x * 64;
    char* Ab = (char*)As;

    #pragma unroll
    for (int i = 0; i < 8; ++i) {
        int flat = i * 256 + tid;            // 16B-chunk id 0..2047
        int r = flat >> 5;                   // row 0..63 (32 chunks/row)
        int cb = (flat & 31) * 16;
        int gr = rowbase + r; if (gr >= N_NODES) gr = N_NODES - 1;
        int4 v = *reinterpret_cast<const int4*>(a1b + (size_t)gr * 256 + (cb >> 1));
        *reinterpret_cast<int4*>(Ab + r * 512 + (cb ^ ((r & 7) << 4))) = v;
    }
    __syncthreads();

    const int lm = l & 15, lh = l >> 4;
    f32x4 acc[4];
    #pragma unroll
    for (int rt = 0; rt < 4; ++rt) acc[rt] = (f32x4){0.f, 0.f, 0.f, 0.f};

    #pragma unroll
    for (int s = 0; s < 8; ++s) {
        int n = w * 16 + lm;
        bf16x8 bf = *reinterpret_cast<const bf16x8*>(w2t + n * 256 + s * 32 + lh * 8);
        #pragma unroll
        for (int rt = 0; rt < 4; ++rt) {
            int row = rt * 16 + lm;
            int cb = s * 64 + lh * 16;
            bf16x8 af = *reinterpret_cast<const bf16x8*>(Ab + row * 512 + (cb ^ ((row & 7) << 4)));
            acc[rt] = __builtin_amdgcn_mfma_f32_16x16x32_bf16(bf, af, acc[rt], 0, 0, 0);
        }
    }

    #pragma unroll
    for (int rt = 0; rt < 4; ++rt) {
        int row = rowbase + rt * 16 + lm;
        int col = w * 16 + lh * 4;
        float ps = 0.f, pd = 0.f;
        if (row < N_NODES) {
            ushort4 o;
            o.x = f2bf(acc[rt][0]); o.y = f2bf(acc[rt][1]);
            o.z = f2bf(acc[rt][2]); o.w = f2bf(acc[rt][3]);
            *reinterpret_cast<ushort4*>(h2 + (size_t)row * 64 + col) = o;
        }
        #pragma unroll
        for (int q = 0; q < 4; ++q) {
            ps += acc[rt][q] * att_src[col + q];
            pd += acc[rt][q] * att_dst[col + q];
        }
        ps += __shfl_xor(ps, 16); ps += __shfl_xor(ps, 32);
        pd += __shfl_xor(pd, 16); pd += __shfl_xor(pd, 32);
        if (lh == 0) { ps_s[w][rt * 16 + lm] = ps; pd_s[w][rt * 16 + lm] = pd; }
    }
    __syncthreads();
    if (tid < 64) {
        int row = rowbase + tid;
        if (row < N_NODES) {
            a_src[row] = ps_s[0][tid] + ps_s[1][tid] + ps_s[2][tid] + ps_s[3][tid];
            a_dst[row] = pd_s[0][tid] + pd_s[1][tid] + pd_s[2][tid] + pd_s[3][tid];
        }
    }
}

// ---------------- GAT layer-1 aggregation (4 heads x 64 ch), no-max softmax, bf16 out ----------------
__global__ __launch_bounds__(256) void gat_agg1(const unsigned short* __restrict__ h1,
                                                const float* __restrict__ a_src,
                                                const float* __restrict__ a_dst,
                                                const int* __restrict__ rowstart,
                                                const int* __restrict__ srcidx,
                                                const float* __restrict__ b1,
                                                unsigned short* __restrict__ out1) {
    int n = (blockIdx.x * 256 + threadIdx.x) >> 6;
    int lane = threadIdx.x & 63;
    if (n >= N_NODES) return;
    int beg = rowstart[n], end = rowstart[n + 1];
    const int h    = lane & 3;    // head this lane evaluates edge-weights for
    const int slot = lane >> 2;   // edge slot 0..15 within a chunk
    const int myhead = lane >> 4; // head of this lane's output channels
    float ad_h = a_dst[n * 4 + h];

    float4 acc = make_float4(0.f, 0.f, 0.f, 0.f);
    float den_part = 0.f;
    int cb = beg;
    for (; cb + 16 <= end; cb += 16) {          // full chunks: static inner loop
        int s = srcidx[cb + slot];
        float w = __expf(lrelu(a_src[s * 4 + h] + ad_h));   // bounded logits: no max needed
        den_part += w;
        #pragma unroll
        for (int j = 0; j < 16; ++j) {
            float wj = __shfl(w, j * 4 + myhead);
            int   sj = __shfl(s, j * 4);
            ushort4 hv = *reinterpret_cast<const ushort4*>(&h1[(size_t)sj * 256 + lane * 4]);
            acc.x += wj * bf2f(hv.x); acc.y += wj * bf2f(hv.y);
            acc.z += wj * bf2f(hv.z); acc.w += wj * bf2f(hv.w);
        }
    }
    if (cb < end) {                              // tail chunk
        int cnt = end - cb;                      // 1..15
        float w = 0.f; int s = 0;
        if (slot < cnt) {
            s = srcidx[cb + slot];
            w = __expf(lrelu(a_src[s * 4 + h] + ad_h));
            den_part += w;
        }
        for (int j = 0; j < cnt; ++j) {
            float wj = __shfl(w, j * 4 + myhead);
            int   sj = __shfl(s, j * 4);
            ushort4 hv = *reinterpret_cast<const ushort4*>(&h1[(size_t)sj * 256 + lane * 4]);
            acc.x += wj * bf2f(hv.x); acc.y += wj * bf2f(hv.y);
            acc.z += wj * bf2f(hv.z); acc.w += wj * bf2f(hv.w);
        }
    }
    #pragma unroll
    for (int off = 4; off < 64; off <<= 1) den_part += __shfl_xor(den_part, off);
    float den = __shfl(den_part, myhead);
    float inv = 1.f / den;
    float4 bv = *reinterpret_cast<const float4*>(&b1[lane * 4]);
    ushort4 o;
    o.x = f2bf(fmaxf(acc.x * inv + bv.x, 0.f));
    o.y = f2bf(fmaxf(acc.y * inv + bv.y, 0.f));
    o.z = f2bf(fmaxf(acc.z * inv + bv.z, 0.f));
    o.w = f2bf(fmaxf(acc.w * inv + bv.w, 0.f));
    *reinterpret_cast<ushort4*>(&out1[(size_t)n * 256 + lane * 4]) = o;
}

// ---------------- GAT layer-2 aggregation (1 head) + fused global max pool ----------------
__global__ __launch_bounds__(256) void gat_agg2_pool(const unsigned short* __restrict__ h2,
                                                     const float* __restrict__ a_src,
                                                     const float* __restrict__ a_dst,
                                                     const int* __restrict__ rowstart,
                                                     const int* __restrict__ srcidx,
                                                     const float* __restrict__ b2,
                                                     const int* __restrict__ batch,
                                                     unsigned* __restrict__ g) {
    __shared__ float sm[4][64];
    const int wid = threadIdx.x >> 6;
    const int lane = threadIdx.x & 63;
    const int n = blockIdx.x * 4 + wid;
    const int grp = lane >> 4;                   // edge sub-slot 0..3
    const int cl  = lane & 15;                   // channel quad 0..15
    int beg = rowstart[n], end = rowstart[n + 1];
    float ad = a_dst[n];

    float4 acc = make_float4(0.f, 0.f, 0.f, 0.f);
    float den_part = 0.f;
    int cb = beg;
    for (; cb + 16 <= end; cb += 16) {
        float w = 0.f; int s = 0;
        if (lane < 16) {
            s = srcidx[cb + lane];
            w = __expf(lrelu(a_src[s] + ad));    // bounded logits: no max needed
            den_part += w;
        }
        #pragma unroll
        for (int j = 0; j < 16; j += 4) {
            float wj = __shfl(w, j + grp);
            int   sj = __shfl(s, j + grp);
            ushort4 hv = *reinterpret_cast<const ushort4*>(&h2[(size_t)sj * 64 + cl * 4]);
            acc.x += wj * bf2f(hv.x); acc.y += wj * bf2f(hv.y);
            acc.z += wj * bf2f(hv.z); acc.w += wj * bf2f(hv.w);
        }
    }
    if (cb < end) {
        int cnt = end - cb;
        float w = 0.f; int s = 0;
        if (lane < cnt) {
            s = srcidx[cb + lane];
            w = __expf(lrelu(a_src[s] + ad));
            den_part += w;
        }
        for (int j = 0; j < cnt; j += 4) {
            float wj = __shfl(w, j + grp);
            int   sj = __shfl(s, j + grp);
            if (j + grp < cnt) {
                ushort4 hv = *reinterpret_cast<const ushort4*>(&h2[(size_t)sj * 64 + cl * 4]);
                acc.x += wj * bf2f(hv.x); acc.y += wj * bf2f(hv.y);
                acc.z += wj * bf2f(hv.z); acc.w += wj * bf2f(hv.w);
            }
        }
    }
    #pragma unroll
    for (int off = 16; off < 64; off <<= 1) {
        acc.x += __shfl_xor(acc.x, off);
        acc.y += __shfl_xor(acc.y, off);
        acc.z += __shfl_xor(acc.z, off);
        acc.w += __shfl_xor(acc.w, off);
    }
    #pragma unroll
    for (int off = 1; off < 64; off <<= 1) den_part += __shfl_xor(den_part, off);
    float inv = 1.f / den_part;
    float4 bv = *reinterpret_cast<const float4*>(&b2[cl * 4]);
    if (lane < 16) {
        float4 val;
        val.x = fmaxf(acc.x * inv + bv.x, 0.f);
        val.y = fmaxf(acc.y * inv + bv.y, 0.f);
        val.z = fmaxf(acc.z * inv + bv.z, 0.f);
        val.w = fmaxf(acc.w * inv + bv.w, 0.f);
        *reinterpret_cast<float4*>(&sm[wid][cl * 4]) = val;
    }
    __syncthreads();
    int b0 = batch[blockIdx.x * 4];
    int b3 = batch[blockIdx.x * 4 + 3];
    if (b0 == b3) {
        if (threadIdx.x < 64) {
            float v = fmaxf(fmaxf(sm[0][threadIdx.x], sm[1][threadIdx.x]),
                            fmaxf(sm[2][threadIdx.x], sm[3][threadIdx.x]));
            atomicMax(&g[b0 * 64 + threadIdx.x], __float_as_uint(v));
        }
    } else {
        if (lane < 16) {
            int bb = batch[n];
            #pragma unroll
            for (int k = 0; k < 4; ++k)
                atomicMax(&g[bb * 64 + cl * 4 + k], __float_as_uint(sm[wid][cl * 4 + k]));
        }
    }
}

// ---------------- MLP head + log_softmax ----------------
__global__ __launch_bounds__(256) void head_kernel(const float* __restrict__ g,
                                                   const float* __restrict__ w_fc1,
                                                   const float* __restrict__ b_fc1,
                                                   const float* __restrict__ w_fc2,
                                                   const float* __restrict__ b_fc2,
                                                   float* __restrict__ out) {
    __shared__ float gs[64][65];
    __shared__ float hs[64][65];
    int t = threadIdx.x;
    #pragma unroll
    for (int it = 0; it < 16; ++it) {
        int flat = it * 256 + t;
        gs[flat >> 6][flat & 63] = g[flat];
    }
    __syncthreads();
    #pragma unroll
    for (int it = 0; it < 16; ++it) {
        int flat = it * 256 + t;
        int i = flat >> 6, j = flat & 63;
        float s = b_fc1[j];
        #pragma unroll 8
        for (int k = 0; k < 64; ++k) s += gs[i][k] * w_fc1[k * 64 + j];
        hs[i][j] = fmaxf(s, 0.f);
    }
    __syncthreads();
    if (t < 64) {
        float l0 = b_fc2[0], l1 = b_fc2[1];
        #pragma unroll 8
        for (int k = 0; k < 64; ++k) {
            float v = hs[t][k];
            l0 += v * w_fc2[k * 2];
            l1 += v * w_fc2[k * 2 + 1];
        }
        float mx = fmaxf(l0, l1);
        float lse = mx + logf(__expf(l0 - mx) + __expf(l1 - mx));
        out[t * 2]     = l0 - lse;
        out[t * 2 + 1] = l1 - lse;
    }
}

extern "C" void kernel_launch(void* const* d_in, const int* in_sizes, int n_in,
                              void* d_out, int out_size, void* d_ws, size_t ws_size,
                              hipStream_t stream) {
    const float* x        = (const float*)d_in[0];
    const int*   ei       = (const int*)d_in[1];
    const int*   batch    = (const int*)d_in[2];
    const float* W1       = (const float*)d_in[3];
    const float* att_src1 = (const float*)d_in[4];
    const float* att_dst1 = (const float*)d_in[5];
    const float* b1       = (const float*)d_in[6];
    const float* W2       = (const float*)d_in[7];
    const float* att_src2 = (const float*)d_in[8];
    const float* att_dst2 = (const float*)d_in[9];
    const float* b2       = (const float*)d_in[10];
    const float* w_fc1    = (const float*)d_in[11];
    const float* b_fc1    = (const float*)d_in[12];
    const float* w_fc2    = (const float*)d_in[13];
    const float* b_fc2    = (const float*)d_in[14];

    char* ws = (char*)d_ws;
    size_t off = 0;
    auto alloc = [&](size_t bytes) -> char* {
        char* p = ws + off;
        off += (bytes + 255) & ~(size_t)255;
        return p;
    };
    unsigned short* xb   = (unsigned short*)alloc((size_t)N_NODES * 128 * 2);
    unsigned short* w1t  = (unsigned short*)alloc((size_t)256 * 128 * 2);
    unsigned short* w2t  = (unsigned short*)alloc((size_t)64 * 256 * 2);
    unsigned short* h1   = (unsigned short*)alloc((size_t)N_NODES * 256 * 2);
    unsigned short* out1 = (unsigned short*)alloc((size_t)N_NODES * 256 * 2);
    unsigned short* h2   = (unsigned short*)alloc((size_t)N_NODES * 64 * 2);
    float*    as1        = (float*)alloc((size_t)N_NODES * 4 * 4);
    float*    ad1        = (float*)alloc((size_t)N_NODES * 4 * 4);
    float*    as2        = (float*)alloc((size_t)N_NODES * 4);
    float*    ad2        = (float*)alloc((size_t)N_NODES * 4);
    int*      counts     = (int*)alloc((size_t)N_NODES * 4);
    int*      rowstart   = (int*)alloc((size_t)(N_NODES + 4) * 4);
    int*      cursor     = (int*)alloc((size_t)(N_NODES + 4) * 4);
    int*      srcidx     = (int*)alloc((size_t)E_TOT * 4);
    unsigned* g          = (unsigned*)alloc((size_t)N_GRAPHS * HID * 4);

    // init + conversions
    zero_kernel<<<(N_NODES + 255) / 256, 256, 0, stream>>>(counts, g);
    conv_x_kernel<<<(N_NODES * 128 / 4 + 255) / 256, 256, 0, stream>>>(x, xb);
    conv_w_kernel<<<192, 256, 0, stream>>>(W1, W2, w1t, w2t);

    // CSR by dst (shared by both layers)
    edge_hist<<<(E_TOT + 255) / 256, 256, 0, stream>>>(ei, counts);
    scan_counts<<<1, 1024, 0, stream>>>(counts, rowstart, cursor);
    edge_scatter<<<(E_TOT + 255) / 256, 256, 0, stream>>>(ei, cursor, srcidx);

    // layer 1
    mfma_gemm1<<<(N_NODES + 63) / 64, 256, 0, stream>>>(xb, w1t, h1, att_src1, att_dst1, as1, ad1);
    gat_agg1<<<7500, 256, 0, stream>>>(h1, as1, ad1, rowstart, srcidx, b1, out1);

    // layer 2
    mfma_gemm2<<<(N_NODES + 63) / 64, 256, 0, stream>>>(out1, w2t, h2, att_src2, att_dst2, as2, ad2);
    gat_agg2_pool<<<7500, 256, 0, stream>>>(h2, as2, ad2, rowstart, srcidx, b2, batch, g);

    // head
    head_kernel<<<1, 256, 0, stream>>>((const float*)g, w_fc1, b_fc1, w_fc2, b_fc2, (float*)d_out);
}